// Round 11
// baseline (374.973 us; speedup 1.0000x reference)
//
#include <hip/hip_runtime.h>
#include <math.h>

#define Bm 2048
#define Hm 512
#define Em 300
#define Tm 50
#define KWm 812   // H + E
#define KWp 832   // padded to multiple of 32

typedef unsigned short u16;
typedef unsigned int u32;
typedef __attribute__((ext_vector_type(8))) short short8;
typedef __attribute__((ext_vector_type(8))) u16 ushort8v;
typedef __attribute__((ext_vector_type(4))) float f32x4;

__device__ __forceinline__ float sigmoidf_(float x) { return 1.f / (1.f + __expf(-x)); }
// fast tanh: exact at saturation, ~6 VALU ops (vs ~25-40 for libm tanhf)
__device__ __forceinline__ float tanhfast(float x) { return 1.f - 2.f / (__expf(2.f * x) + 1.f); }

// fp32 -> bf16 bits, round-to-nearest-even
__device__ __forceinline__ u16 bfr(float x) {
    union { float f; u32 u; } c; c.f = x;
    u32 u = c.u;
    u += 0x7FFFu + ((u >> 16) & 1u);
    return (u16)(u >> 16);
}
__device__ __forceinline__ ushort8v pk8(f32x4 v0, f32x4 v1) {
    ushort8v r;
    r[0] = bfr(v0[0]); r[1] = bfr(v0[1]); r[2] = bfr(v0[2]); r[3] = bfr(v0[3]);
    r[4] = bfr(v1[0]); r[5] = bfr(v1[1]); r[6] = bfr(v1[2]); r[7] = bfr(v1[3]);
    return r;
}

// async global(bf16,16B) -> LDS, linear dest (wave-uniform base + lane*16)
__device__ __forceinline__ void gload16(const u16* g, u16* l) {
    __builtin_amdgcn_global_load_lds((const __attribute__((address_space(1))) void*)g,
                                     (__attribute__((address_space(3))) void*)l, 16, 0, 0);
}

// ---------------------------------------------------------------------------
// k_pack: small bf16 conversions/concats.
// job 0: Aq[2048][1024] = bf16([h_enc | h_summ])
// job 1: Wq[512][1024]  = bf16([lq_w | ls_w])
// job 2: Wg[2048][832]  = bf16(W_w) zero-padded
// job 3: Xb[2048][512..831] = bf16(x) zero-padded
// job 4: lkwb[512][512] = bf16(lk_w)
// ---------------------------------------------------------------------------
__global__ __launch_bounds__(256) void k_pack(
        const float* __restrict__ henc, const float* __restrict__ hsum,
        const float* __restrict__ lq, const float* __restrict__ ls,
        const float* __restrict__ Ww, const float* __restrict__ x,
        const float* __restrict__ lkw,
        u16* __restrict__ Aq, u16* __restrict__ Wq,
        u16* __restrict__ Wg, u16* __restrict__ Xb, u16* __restrict__ lkwb) {
    const int job = blockIdx.y;
    const int r = blockIdx.x;
    const int tid = threadIdx.x;
    if (job == 0) {
        for (int c = tid; c < 1024; c += 256) {
            float v = (c < 512) ? henc[(size_t)r * 512 + c] : hsum[(size_t)r * 512 + (c - 512)];
            Aq[(size_t)r * 1024 + c] = bfr(v);
        }
    } else if (job == 1) {
        if (r < 512)
            for (int c = tid; c < 1024; c += 256) {
                float v = (c < 512) ? lq[(size_t)r * 512 + c] : ls[(size_t)r * 512 + (c - 512)];
                Wq[(size_t)r * 1024 + c] = bfr(v);
            }
    } else if (job == 2) {
        for (int c = tid; c < KWp; c += 256)
            Wg[(size_t)r * KWp + c] = (c < KWm) ? bfr(Ww[(size_t)r * KWm + c]) : (u16)0;
    } else if (job == 3) {
        for (int c = 512 + tid; c < KWp; c += 256)
            Xb[(size_t)r * KWp + c] = (c < KWm) ? bfr(x[(size_t)r * Em + (c - 512)]) : (u16)0;
    } else {
        if (r < 512)
            for (int c = tid; c < 512; c += 256)
                lkwb[(size_t)r * 512 + c] = bfr(lkw[(size_t)r * 512 + c]);
    }
}

// ---------------------------------------------------------------------------
// k_qs_mfma: qs[b,h] = [h_enc|h_summ]·[lq|ls]^T + (lq_b+ls_b+lk_b)[h]
// ---------------------------------------------------------------------------
__global__ __launch_bounds__(256) void k_qs_mfma(
        const u16* __restrict__ Aq, const u16* __restrict__ Wq,
        const float* __restrict__ lqb, const float* __restrict__ lsb,
        const float* __restrict__ lkb, float* __restrict__ qs) {
    __shared__ u16 Asl[64 * 32];
    __shared__ u16 Bsl[64 * 32];
    const int m0 = blockIdx.x * 64, n0 = blockIdx.y * 64;
    const int tid = threadIdx.x, lane = tid & 63, wid = tid >> 6;
    const int wr = wid >> 1, wc = wid & 1;
    const int l15 = lane & 15, l4 = lane >> 4;
    const int srow = (wid << 4) + (lane >> 2);
    const int gchunk = (lane & 3) ^ ((srow >> 1) & 3);
    f32x4 acc[2][2];
    #pragma unroll
    for (int i = 0; i < 2; ++i)
        #pragma unroll
        for (int j = 0; j < 2; ++j) acc[i][j] = (f32x4){0.f, 0.f, 0.f, 0.f};

    for (int k0 = 0; k0 < 1024; k0 += 32) {
        __syncthreads();
        gload16(Aq + (size_t)(m0 + srow) * 1024 + k0 + gchunk * 8, &Asl[wid * 512]);
        gload16(Wq + (size_t)(n0 + srow) * 1024 + k0 + gchunk * 8, &Bsl[wid * 512]);
        __syncthreads();
        short8 af[2], bf[2];
        #pragma unroll
        for (int mf = 0; mf < 2; ++mf) {
            int r = wr * 32 + mf * 16 + l15;
            af[mf] = *(const short8*)&Asl[r * 32 + (l4 ^ ((r >> 1) & 3)) * 8];
        }
        #pragma unroll
        for (int nf = 0; nf < 2; ++nf) {
            int r = wc * 32 + nf * 16 + l15;
            bf[nf] = *(const short8*)&Bsl[r * 32 + (l4 ^ ((r >> 1) & 3)) * 8];
        }
        #pragma unroll
        for (int mf = 0; mf < 2; ++mf)
            #pragma unroll
            for (int nf = 0; nf < 2; ++nf)
                acc[mf][nf] = __builtin_amdgcn_mfma_f32_16x16x32_bf16(
                                  af[mf], bf[nf], acc[mf][nf], 0, 0, 0);
    }
    #pragma unroll
    for (int mf = 0; mf < 2; ++mf)
        #pragma unroll
        for (int nf = 0; nf < 2; ++nf)
            #pragma unroll
            for (int reg = 0; reg < 4; ++reg) {
                int b = m0 + wr * 32 + mf * 16 + l4 * 4 + reg;
                int h = n0 + wc * 32 + nf * 16 + l15;
                qs[(size_t)b * Hm + h] = acc[mf][nf][reg] + lqb[h] + lsb[h] + lkb[h];
            }
}

// ---------------------------------------------------------------------------
// k_scores_mfma (dominant) R11: R7 structure (best measured, 162us) + fused
// phi fp32->bf16 pack. scores is latency-bound (HBM 4-6%, VALU ~25% idle),
// so the 315MB pack_phi pass rides along ~free:
//  - A staged by reg-loading fp32 phi, bfr-convert, swizzled ds_write_b128
//    (LDS[row][slot = chunk ^ (row&7)] - same involution R7's reads expect).
//  - n0==0 block of each m-panel also stores its converted rows to phib
//    (global bf16) for k_attn. Every phi row converted exactly once.
//  - B staging unchanged: gload16 with source-side swizzle.
// BK=64, 8 K-iters, drain __syncthreads, XCD-bijective swizzle, setprio(1)
// around MFMA, fused fast-tanh/v_w/row-sum epilogue, atomicAdd into scores.
// ---------------------------------------------------------------------------
__global__ __launch_bounds__(256) void k_scores_mfma(
        const float* __restrict__ phi, const u16* __restrict__ lkwb,
        const float* __restrict__ qs2, const float* __restrict__ vw,
        float* __restrict__ scores, u16* __restrict__ phib) {
    __shared__ u16 Asl[128 * 64];
    __shared__ u16 Bsl[128 * 64];
    // XCD swizzle: HW round-robins consecutive dispatch ids over 8 XCDs.
    const int d  = blockIdx.x;
    const int wg = (d & 7) * 400 + (d >> 3);
    const int n0 = (wg & 3) << 7;          // 4 n-tiles, fastest within XCD
    const int m0 = (wg >> 2) << 7;         // contiguous m-range per XCD
    const int t  = m0 >> 11;
    const int b0 = m0 & (Bm - 1);
    const int tid = threadIdx.x, lane = tid & 63, wid = tid >> 6;
    const int wr = wid >> 1, wc = wid & 1;
    const int l15 = lane & 15, l4 = lane >> 4;
    const int rin = lane >> 3;                 // 0..7 row-in-group
    const int ca  = lane & 7;                  // A chunk slot (8 bf16 = 16B)
    const int schunkB = ca ^ rin;              // B inverse-swizzled source chunk
    const bool wb = (n0 == 0);                 // this block writes phib back

    f32x4 acc[4][4];
    #pragma unroll
    for (int i = 0; i < 4; ++i)
        #pragma unroll
        for (int j = 0; j < 4; ++j) acc[i][j] = (f32x4){0.f, 0.f, 0.f, 0.f};

    for (int kt = 0; kt < 8; ++kt) {
        const int k0 = kt << 6;
        __syncthreads();   // previous iter's reads complete
        // B: async global->LDS (bf16 source), linear dest, source swizzle
        #pragma unroll
        for (int j = 0; j < 4; ++j) {
            int r = (wid << 5) + (j << 3) + rin;        // 0..127
            gload16(lkwb + (size_t)(n0 + r) * 512 + k0 + schunkB * 8,
                    &Bsl[((wid << 5) + (j << 3)) * 64]);
        }
        // A: reg-stage fp32 phi -> bf16, swizzled ds_write; wb blocks also
        // store the converted chunk to phib (the fused pack_phi).
        #pragma unroll
        for (int u = 0; u < 4; ++u) {
            int ra = (wid << 5) + (u << 3) + rin;       // 0..127
            const float* src = phi + (size_t)(m0 + ra) * 512 + k0 + ca * 8;
            f32x4 a0 = *(const f32x4*)src;
            f32x4 a1 = *(const f32x4*)(src + 4);
            ushort8v c8 = pk8(a0, a1);
            if (wb) *(ushort8v*)(phib + (size_t)(m0 + ra) * 512 + k0 + ca * 8) = c8;
            *(ushort8v*)&Asl[ra * 64 + ((ca ^ rin) << 3)] = c8;
        }
        __syncthreads();   // ds_writes + gload_lds visible to all waves
        short8 af[4][2], bf[4][2];
        #pragma unroll
        for (int mf = 0; mf < 4; ++mf) {
            int r = wr * 64 + mf * 16 + l15;
            #pragma unroll
            for (int ks = 0; ks < 2; ++ks) {
                int c = ks * 4 + l4;
                af[mf][ks] = *(const short8*)&Asl[r * 64 + (c ^ (r & 7)) * 8];
            }
        }
        #pragma unroll
        for (int nf = 0; nf < 4; ++nf) {
            int r = wc * 64 + nf * 16 + l15;
            #pragma unroll
            for (int ks = 0; ks < 2; ++ks) {
                int c = ks * 4 + l4;
                bf[nf][ks] = *(const short8*)&Bsl[r * 64 + (c ^ (r & 7)) * 8];
            }
        }
        __builtin_amdgcn_s_setprio(1);
        #pragma unroll
        for (int ks = 0; ks < 2; ++ks)
            #pragma unroll
            for (int mf = 0; mf < 4; ++mf)
                #pragma unroll
                for (int nf = 0; nf < 4; ++nf)
                    acc[mf][nf] = __builtin_amdgcn_mfma_f32_16x16x32_bf16(
                                      af[mf][ks], bf[nf][ks], acc[mf][nf], 0, 0, 0);
        __builtin_amdgcn_s_setprio(0);
    }

    // epilogue: fast tanh + v_w dot + row-sum, one atomicAdd per row per wave
    float vws[4];
    int av[4];
    #pragma unroll
    for (int nf = 0; nf < 4; ++nf) {
        av[nf] = n0 + wc * 64 + nf * 16 + l15;
        vws[nf] = vw[av[nf]];
    }
    #pragma unroll
    for (int mf = 0; mf < 4; ++mf) {
        #pragma unroll
        for (int reg = 0; reg < 4; ++reg) {
            int b = b0 + wr * 64 + mf * 16 + l4 * 4 + reg;
            const float* q = qs2 + (size_t)b * Hm;
            float s = 0.f;
            #pragma unroll
            for (int nf = 0; nf < 4; ++nf)
                s = fmaf(tanhfast(acc[mf][nf][reg] + q[av[nf]]), vws[nf], s);
            #pragma unroll
            for (int o = 1; o < 16; o <<= 1) s += __shfl_xor(s, o);
            if (l15 == 0) atomicAdd(&scores[(size_t)b * Tm + t], s);
        }
    }
}

// ---------------------------------------------------------------------------
// k_attn: softmax over T, weighted sums over bf16 phi + fp32 cell.
// ---------------------------------------------------------------------------
__global__ __launch_bounds__(256) void k_attn(
        const u16* __restrict__ phib, const float* __restrict__ cell,
        const float* __restrict__ scores,
        u16* __restrict__ Xb, float* __restrict__ cs) {
    __shared__ float p[Tm];
    const int b = blockIdx.x;
    const int tid = threadIdx.x;
    if (tid < 64) {
        float s = (tid < Tm) ? scores[(size_t)b * Tm + tid] : -INFINITY;
        float m = s;
        #pragma unroll
        for (int o = 32; o; o >>= 1) m = fmaxf(m, __shfl_xor(m, o));
        float ex = (tid < Tm) ? __expf(s - m) : 0.f;
        float sum = ex;
        #pragma unroll
        for (int o = 32; o; o >>= 1) sum += __shfl_xor(sum, o);
        if (tid < Tm) p[tid] = ex / sum;
    }
    __syncthreads();
    const int c0 = tid * 2;
    float ah0 = 0.f, ah1 = 0.f, ac0 = 0.f, ac1 = 0.f;
    for (int t = 0; t < Tm; ++t) {
        float w = p[t];
        const size_t rb = ((size_t)t * Bm + b) * 512 + c0;
        u32 ph2 = *(const u32*)&phib[rb];
        float2 ce2 = *(const float2*)&cell[rb];
        float p0 = __uint_as_float(ph2 << 16);
        float p1 = __uint_as_float(ph2 & 0xFFFF0000u);
        ah0 = fmaf(w, p0, ah0);
        ah1 = fmaf(w, p1, ah1);
        ac0 = fmaf(w, ce2.x, ac0);
        ac1 = fmaf(w, ce2.y, ac1);
    }
    *(u32*)&Xb[(size_t)b * KWp + c0] = (u32)bfr(ah0) | ((u32)bfr(ah1) << 16);
    *(float2*)&cs[(size_t)b * Hm + c0] = make_float2(ac0, ac1);
}

// ---------------------------------------------------------------------------
// k_gates_mfma: gates[2048][2048] = Xb(2048x832) @ Wg^T(2048x832), bf16 MFMA.
// ---------------------------------------------------------------------------
__global__ __launch_bounds__(256) void k_gates_mfma(
        const u16* __restrict__ Xb, const u16* __restrict__ Wg,
        float* __restrict__ gates) {
    __shared__ u16 Asl[64 * 32];
    __shared__ u16 Bsl[128 * 32];
    const int m0 = blockIdx.x * 64, n0 = blockIdx.y * 128;
    const int tid = threadIdx.x, lane = tid & 63, wid = tid >> 6;
    const int wr = wid >> 1, wc = wid & 1;
    const int l15 = lane & 15, l4 = lane >> 4;
    const int srow = (wid << 4) + (lane >> 2);
    const int gchunkA = (lane & 3) ^ ((srow >> 1) & 3);
    f32x4 acc[2][4];
    #pragma unroll
    for (int i = 0; i < 2; ++i)
        #pragma unroll
        for (int j = 0; j < 4; ++j) acc[i][j] = (f32x4){0.f, 0.f, 0.f, 0.f};

    for (int k0 = 0; k0 < KWp; k0 += 32) {
        __syncthreads();
        gload16(Xb + (size_t)(m0 + srow) * KWp + k0 + gchunkA * 8, &Asl[wid * 512]);
        #pragma unroll
        for (int j = 0; j < 2; ++j) {
            int brow = (wid << 5) + (j << 4) + (lane >> 2);
            int gchunkB = (lane & 3) ^ ((brow >> 1) & 3);
            gload16(Wg + (size_t)(n0 + brow) * KWp + k0 + gchunkB * 8,
                    &Bsl[wid * 1024 + j * 512]);
        }
        __syncthreads();
        short8 af[2], bf[4];
        #pragma unroll
        for (int mf = 0; mf < 2; ++mf) {
            int r = wr * 32 + mf * 16 + l15;
            af[mf] = *(const short8*)&Asl[r * 32 + (l4 ^ ((r >> 1) & 3)) * 8];
        }
        #pragma unroll
        for (int nf = 0; nf < 4; ++nf) {
            int r = wc * 64 + nf * 16 + l15;
            bf[nf] = *(const short8*)&Bsl[r * 32 + (l4 ^ ((r >> 1) & 3)) * 8];
        }
        #pragma unroll
        for (int mf = 0; mf < 2; ++mf)
            #pragma unroll
            for (int nf = 0; nf < 4; ++nf)
                acc[mf][nf] = __builtin_amdgcn_mfma_f32_16x16x32_bf16(
                                  af[mf], bf[nf], acc[mf][nf], 0, 0, 0);
    }
    #pragma unroll
    for (int mf = 0; mf < 2; ++mf)
        #pragma unroll
        for (int nf = 0; nf < 4; ++nf)
            #pragma unroll
            for (int reg = 0; reg < 4; ++reg) {
                int b = m0 + wr * 32 + mf * 16 + l4 * 4 + reg;
                int n = n0 + wc * 64 + nf * 16 + l15;
                gates[(size_t)b * 2048 + n] = acc[mf][nf][reg];
            }
}

// ---------------------------------------------------------------------------
// k_lstm: elementwise LSTM epilogue over [B,H].
// ---------------------------------------------------------------------------
__global__ __launch_bounds__(256) void k_lstm(
        const float* __restrict__ gates, const float* __restrict__ Wb,
        const float* __restrict__ cs, float* __restrict__ out) {
    const int idx = blockIdx.x * 256 + threadIdx.x;
    const int b = idx >> 9, h = idx & 511;
    const float* g = gates + (size_t)b * 2048;
    float f  = sigmoidf_(g[h]        + Wb[h]);
    float o  = sigmoidf_(g[512 + h]  + Wb[512 + h]);
    float ii = sigmoidf_(g[1024 + h] + Wb[1024 + h]);
    float ch = tanhfast( g[1536 + h] + Wb[1536 + h]);
    float c  = f * cs[idx] + ii * ch;
    out[idx] = o * tanhfast(c);
}

extern "C" void kernel_launch(void* const* d_in, const int* in_sizes, int n_in,
                              void* d_out, int out_size, void* d_ws, size_t ws_size,
                              hipStream_t stream) {
    const float* x      = (const float*)d_in[0];
    const float* h_enc  = (const float*)d_in[1];
    const float* phi    = (const float*)d_in[2];
    const float* cell   = (const float*)d_in[3];
    const float* h_summ = (const float*)d_in[4];
    // d_in[5] c_summ: unused by the reference
    const float* W_w    = (const float*)d_in[6];
    const float* W_b    = (const float*)d_in[7];
    const float* v_w    = (const float*)d_in[8];
    // d_in[9] v_b: softmax-invariant, dropped
    const float* lq_w   = (const float*)d_in[10];
    const float* lq_b   = (const float*)d_in[11];
    const float* lk_w   = (const float*)d_in[12];
    const float* lk_b   = (const float*)d_in[13];
    const float* ls_w   = (const float*)d_in[14];
    const float* ls_b   = (const float*)d_in[15];
    float* out = (float*)d_out;

    char* w = (char*)d_ws;
    // phib: 0 .. 104,857,600 (52.4M bf16), written by k_scores_mfma (fused
    // pack), read by k_attn. gates (16.78 MB) ALIASES phib: phib's last
    // reader (k_attn) finishes before k_gates_mfma writes gates.
    u16*   phib   = (u16*)  (w);
    float* gates  = (float*)(w);
    float* qs     = (float*)(w + 104857600);                // 4.00 MB
    float* scores = (float*)(w + 109051904);                // 0.40 MB
    float* cs     = (float*)(w + 109461504);                // 4.00 MB
    u16*   Aq     = (u16*)  (w + 113655808);                // 4.19 MB
    u16*   Wq     = (u16*)  (w + 117850112);                // 1.05 MB
    u16*   Wg     = (u16*)  (w + 118898688);                // 3.41 MB
    u16*   Xb     = (u16*)  (w + 122306560);                // 3.41 MB
    u16*   lkwb   = (u16*)  (w + 125714432);                // 0.52 MB (end ~126.2 MB)

    hipMemsetAsync(scores, 0, (size_t)Bm * Tm * sizeof(float), stream);
    k_pack<<<dim3(2048, 5), 256, 0, stream>>>(h_enc, h_summ, lq_w, ls_w, W_w, x, lk_w,
                                              Aq, Wq, Wg, Xb, lkwb);
    k_qs_mfma<<<dim3(Bm / 64, Hm / 64), 256, 0, stream>>>(Aq, Wq, lq_b, ls_b, lk_b, qs);
    k_scores_mfma<<<dim3(3200), 256, 0, stream>>>(phi, lkwb, qs, v_w, scores, phib);
    k_attn<<<dim3(Bm), 256, 0, stream>>>(phib, cell, scores, Xb, cs);
    k_gates_mfma<<<dim3(Bm / 64, 2048 / 128), 256, 0, stream>>>(Xb, Wg, gates);
    k_lstm<<<dim3((Bm * Hm) / 256), 256, 0, stream>>>(gates, W_b, cs, out);
}

// Round 12
// 312.410 us; speedup vs baseline: 1.2003x; 1.2003x over previous
//
#include <hip/hip_runtime.h>
#include <math.h>

#define Bm 2048
#define Hm 512
#define Em 300
#define Tm 50
#define KWm 812   // H + E
#define KWp 832   // padded to multiple of 32

typedef unsigned short u16;
typedef unsigned int u32;
typedef __attribute__((ext_vector_type(8))) short short8;
typedef __attribute__((ext_vector_type(8))) u16 ushort8v;
typedef __attribute__((ext_vector_type(4))) float f32x4;

__device__ __forceinline__ float sigmoidf_(float x) { return 1.f / (1.f + __expf(-x)); }
// fast tanh: exact at saturation, ~6 VALU ops
__device__ __forceinline__ float tanhfast(float x) { return 1.f - 2.f / (__expf(2.f * x) + 1.f); }

// fp32 -> bf16 bits, round-to-nearest-even
__device__ __forceinline__ u16 bfr(float x) {
    union { float f; u32 u; } c; c.f = x;
    u32 u = c.u;
    u += 0x7FFFu + ((u >> 16) & 1u);
    return (u16)(u >> 16);
}
__device__ __forceinline__ ushort8v cvt8(const float* __restrict__ p) {
    f32x4 v0 = *(const f32x4*)p;
    f32x4 v1 = *(const f32x4*)(p + 4);
    ushort8v r;
    r[0] = bfr(v0[0]); r[1] = bfr(v0[1]); r[2] = bfr(v0[2]); r[3] = bfr(v0[3]);
    r[4] = bfr(v1[0]); r[5] = bfr(v1[1]); r[6] = bfr(v1[2]); r[7] = bfr(v1[3]);
    return r;
}

// async global(bf16,16B) -> LDS, linear dest (wave-uniform base + lane*16)
__device__ __forceinline__ void gload16(const u16* g, u16* l) {
    __builtin_amdgcn_global_load_lds((const __attribute__((address_space(1))) void*)g,
                                     (__attribute__((address_space(3))) void*)l, 16, 0, 0);
}

// ---------------------------------------------------------------------------
// k_pack_phi: phi fp32 [T*B*512] -> bf16, grid-stride, 8 elems/thread/iter.
// ---------------------------------------------------------------------------
__global__ __launch_bounds__(256) void k_pack_phi(
        const float* __restrict__ phi, u16* __restrict__ phib) {
    const size_t nvec = (size_t)Tm * Bm * 512 / 8;
    for (size_t i = (size_t)blockIdx.x * 256 + threadIdx.x; i < nvec;
         i += (size_t)gridDim.x * 256)
        *(ushort8v*)&phib[i * 8] = cvt8(phi + i * 8);
}

// ---------------------------------------------------------------------------
// k_pack: small bf16 conversions/concats.
// job 0: Aq[2048][1024] = bf16([h_enc | h_summ])
// job 1: Wq[512][1024]  = bf16([lq_w | ls_w])
// job 2: Wg[2048][832]  = bf16(W_w) zero-padded
// job 3: Xb[2048][512..831] = bf16(x) zero-padded
// job 4: lkwb[512][512] = bf16(lk_w)
// job 5: qbias[512] = lq_b + ls_b + lk_b   (folded into scores epilogue)
// ---------------------------------------------------------------------------
__global__ __launch_bounds__(256) void k_pack(
        const float* __restrict__ henc, const float* __restrict__ hsum,
        const float* __restrict__ lq, const float* __restrict__ ls,
        const float* __restrict__ Ww, const float* __restrict__ x,
        const float* __restrict__ lkw,
        const float* __restrict__ lqb, const float* __restrict__ lsb,
        const float* __restrict__ lkb,
        u16* __restrict__ Aq, u16* __restrict__ Wq,
        u16* __restrict__ Wg, u16* __restrict__ Xb, u16* __restrict__ lkwb,
        float* __restrict__ qbias) {
    const int job = blockIdx.y;
    const int r = blockIdx.x;
    const int tid = threadIdx.x;
    if (job == 0) {
        for (int c = tid; c < 1024; c += 256) {
            float v = (c < 512) ? henc[(size_t)r * 512 + c] : hsum[(size_t)r * 512 + (c - 512)];
            Aq[(size_t)r * 1024 + c] = bfr(v);
        }
    } else if (job == 1) {
        if (r < 512)
            for (int c = tid; c < 1024; c += 256) {
                float v = (c < 512) ? lq[(size_t)r * 512 + c] : ls[(size_t)r * 512 + (c - 512)];
                Wq[(size_t)r * 1024 + c] = bfr(v);
            }
    } else if (job == 2) {
        for (int c = tid; c < KWp; c += 256)
            Wg[(size_t)r * KWp + c] = (c < KWm) ? bfr(Ww[(size_t)r * KWm + c]) : (u16)0;
    } else if (job == 3) {
        for (int c = 512 + tid; c < KWp; c += 256)
            Xb[(size_t)r * KWp + c] = (c < KWm) ? bfr(x[(size_t)r * Em + (c - 512)]) : (u16)0;
    } else if (job == 4) {
        if (r < 512)
            for (int c = tid; c < 512; c += 256)
                lkwb[(size_t)r * 512 + c] = bfr(lkw[(size_t)r * 512 + c]);
    } else {
        if (r == 0)
            for (int c = tid; c < 512; c += 256)
                qbias[c] = lqb[c] + lsb[c] + lkb[c];
    }
}

// ---------------------------------------------------------------------------
// k_qs_mfma R12: split-K=2 (blockIdx.z picks a 512-K half; 16 iters instead
// of 32 -> halved serialized chain, doubled resident blocks). Accumulates
// via atomicAdd into zeroed qs (GEMM only; biases folded into scores).
// ---------------------------------------------------------------------------
__global__ __launch_bounds__(256) void k_qs_mfma(
        const u16* __restrict__ Aq, const u16* __restrict__ Wq,
        float* __restrict__ qs) {
    __shared__ u16 Asl[64 * 32];
    __shared__ u16 Bsl[64 * 32];
    const int m0 = blockIdx.x * 64, n0 = blockIdx.y * 64;
    const int kbase = blockIdx.z * 512;
    const int tid = threadIdx.x, lane = tid & 63, wid = tid >> 6;
    const int wr = wid >> 1, wc = wid & 1;
    const int l15 = lane & 15, l4 = lane >> 4;
    const int srow = (wid << 4) + (lane >> 2);
    const int gchunk = (lane & 3) ^ ((srow >> 1) & 3);
    f32x4 acc[2][2];
    #pragma unroll
    for (int i = 0; i < 2; ++i)
        #pragma unroll
        for (int j = 0; j < 2; ++j) acc[i][j] = (f32x4){0.f, 0.f, 0.f, 0.f};

    for (int k0 = kbase; k0 < kbase + 512; k0 += 32) {
        __syncthreads();
        gload16(Aq + (size_t)(m0 + srow) * 1024 + k0 + gchunk * 8, &Asl[wid * 512]);
        gload16(Wq + (size_t)(n0 + srow) * 1024 + k0 + gchunk * 8, &Bsl[wid * 512]);
        __syncthreads();
        short8 af[2], bf[2];
        #pragma unroll
        for (int mf = 0; mf < 2; ++mf) {
            int r = wr * 32 + mf * 16 + l15;
            af[mf] = *(const short8*)&Asl[r * 32 + (l4 ^ ((r >> 1) & 3)) * 8];
        }
        #pragma unroll
        for (int nf = 0; nf < 2; ++nf) {
            int r = wc * 32 + nf * 16 + l15;
            bf[nf] = *(const short8*)&Bsl[r * 32 + (l4 ^ ((r >> 1) & 3)) * 8];
        }
        #pragma unroll
        for (int mf = 0; mf < 2; ++mf)
            #pragma unroll
            for (int nf = 0; nf < 2; ++nf)
                acc[mf][nf] = __builtin_amdgcn_mfma_f32_16x16x32_bf16(
                                  af[mf], bf[nf], acc[mf][nf], 0, 0, 0);
    }
    #pragma unroll
    for (int mf = 0; mf < 2; ++mf)
        #pragma unroll
        for (int nf = 0; nf < 2; ++nf)
            #pragma unroll
            for (int reg = 0; reg < 4; ++reg) {
                int b = m0 + wr * 32 + mf * 16 + l4 * 4 + reg;
                int h = n0 + wc * 32 + nf * 16 + l15;
                atomicAdd(&qs[(size_t)b * Hm + h], acc[mf][nf][reg]);
            }
}

// ---------------------------------------------------------------------------
// k_scores_mfma (dominant) — R7 structure, best measured (162us):
// BK=64 -> 8 K-iters, single-buffered 32KB LDS, drain __syncthreads,
// 8-chunk XOR swizzle (both-sides involution), XCD-bijective block swizzle,
// setprio(1) around MFMA. Fused fast-tanh/v_w/row-sum epilogue (+qbias),
// atomicAdd into scores.
// ---------------------------------------------------------------------------
__global__ __launch_bounds__(256) void k_scores_mfma(
        const u16* __restrict__ phib, const u16* __restrict__ lkwb,
        const float* __restrict__ qs2, const float* __restrict__ vw,
        const float* __restrict__ qbias, float* __restrict__ scores) {
    __shared__ u16 Asl[128 * 64];
    __shared__ u16 Bsl[128 * 64];
    // XCD swizzle: HW round-robins consecutive dispatch ids over 8 XCDs.
    const int d  = blockIdx.x;
    const int wg = (d & 7) * 400 + (d >> 3);
    const int n0 = (wg & 3) << 7;          // 4 n-tiles, fastest within XCD
    const int m0 = (wg >> 2) << 7;         // contiguous m-range per XCD
    const int t  = m0 >> 11;
    const int b0 = m0 & (Bm - 1);
    const int tid = threadIdx.x, lane = tid & 63, wid = tid >> 6;
    const int wr = wid >> 1, wc = wid & 1;
    const int l15 = lane & 15, l4 = lane >> 4;
    const int srow_in = lane >> 3;                 // 0..7 within 8-row group
    const int schunk  = (lane & 7) ^ srow_in;      // inverse-swizzled source chunk

    f32x4 acc[4][4];
    #pragma unroll
    for (int i = 0; i < 4; ++i)
        #pragma unroll
        for (int j = 0; j < 4; ++j) acc[i][j] = (f32x4){0.f, 0.f, 0.f, 0.f};

    for (int kt = 0; kt < 8; ++kt) {
        const int k0 = kt << 6;
        __syncthreads();   // previous iter's reads complete
        #pragma unroll
        for (int j = 0; j < 4; ++j) {
            int r = (wid << 5) + (j << 3) + srow_in;        // 0..127
            gload16(phib + (size_t)(m0 + r) * 512 + k0 + schunk * 8,
                    &Asl[((wid << 5) + (j << 3)) * 64]);
            gload16(lkwb + (size_t)(n0 + r) * 512 + k0 + schunk * 8,
                    &Bsl[((wid << 5) + (j << 3)) * 64]);
        }
        __syncthreads();   // drains vmcnt -> tile visible to all waves
        short8 af[4][2], bf[4][2];
        #pragma unroll
        for (int mf = 0; mf < 4; ++mf) {
            int r = wr * 64 + mf * 16 + l15;
            #pragma unroll
            for (int ks = 0; ks < 2; ++ks) {
                int c = ks * 4 + l4;
                af[mf][ks] = *(const short8*)&Asl[r * 64 + (c ^ (r & 7)) * 8];
            }
        }
        #pragma unroll
        for (int nf = 0; nf < 4; ++nf) {
            int r = wc * 64 + nf * 16 + l15;
            #pragma unroll
            for (int ks = 0; ks < 2; ++ks) {
                int c = ks * 4 + l4;
                bf[nf][ks] = *(const short8*)&Bsl[r * 64 + (c ^ (r & 7)) * 8];
            }
        }
        __builtin_amdgcn_s_setprio(1);
        #pragma unroll
        for (int ks = 0; ks < 2; ++ks)
            #pragma unroll
            for (int mf = 0; mf < 4; ++mf)
                #pragma unroll
                for (int nf = 0; nf < 4; ++nf)
                    acc[mf][nf] = __builtin_amdgcn_mfma_f32_16x16x32_bf16(
                                      af[mf][ks], bf[nf][ks], acc[mf][nf], 0, 0, 0);
        __builtin_amdgcn_s_setprio(0);
    }

    // epilogue: fast tanh + v_w dot + row-sum, one atomicAdd per row per wave
    float vws[4], qb[4];
    int av[4];
    #pragma unroll
    for (int nf = 0; nf < 4; ++nf) {
        av[nf] = n0 + wc * 64 + nf * 16 + l15;
        vws[nf] = vw[av[nf]];
        qb[nf]  = qbias[av[nf]];
    }
    #pragma unroll
    for (int mf = 0; mf < 4; ++mf) {
        #pragma unroll
        for (int reg = 0; reg < 4; ++reg) {
            int b = b0 + wr * 64 + mf * 16 + l4 * 4 + reg;
            const float* q = qs2 + (size_t)b * Hm;
            float s = 0.f;
            #pragma unroll
            for (int nf = 0; nf < 4; ++nf)
                s = fmaf(tanhfast(acc[mf][nf][reg] + q[av[nf]] + qb[nf]), vws[nf], s);
            #pragma unroll
            for (int o = 1; o < 16; o <<= 1) s += __shfl_xor(s, o);
            if (l15 == 0) atomicAdd(&scores[(size_t)b * Tm + t], s);
        }
    }
}

// ---------------------------------------------------------------------------
// k_attn: softmax over T, weighted sums over bf16 phi + fp32 cell.
// ---------------------------------------------------------------------------
__global__ __launch_bounds__(256) void k_attn(
        const u16* __restrict__ phib, const float* __restrict__ cell,
        const float* __restrict__ scores,
        u16* __restrict__ Xb, float* __restrict__ cs) {
    __shared__ float p[Tm];
    const int b = blockIdx.x;
    const int tid = threadIdx.x;
    if (tid < 64) {
        float s = (tid < Tm) ? scores[(size_t)b * Tm + tid] : -INFINITY;
        float m = s;
        #pragma unroll
        for (int o = 32; o; o >>= 1) m = fmaxf(m, __shfl_xor(m, o));
        float ex = (tid < Tm) ? __expf(s - m) : 0.f;
        float sum = ex;
        #pragma unroll
        for (int o = 32; o; o >>= 1) sum += __shfl_xor(sum, o);
        if (tid < Tm) p[tid] = ex / sum;
    }
    __syncthreads();
    const int c0 = tid * 2;
    float ah0 = 0.f, ah1 = 0.f, ac0 = 0.f, ac1 = 0.f;
    for (int t = 0; t < Tm; ++t) {
        float w = p[t];
        const size_t rb = ((size_t)t * Bm + b) * 512 + c0;
        u32 ph2 = *(const u32*)&phib[rb];
        float2 ce2 = *(const float2*)&cell[rb];
        float p0 = __uint_as_float(ph2 << 16);
        float p1 = __uint_as_float(ph2 & 0xFFFF0000u);
        ah0 = fmaf(w, p0, ah0);
        ah1 = fmaf(w, p1, ah1);
        ac0 = fmaf(w, ce2.x, ac0);
        ac1 = fmaf(w, ce2.y, ac1);
    }
    *(u32*)&Xb[(size_t)b * KWp + c0] = (u32)bfr(ah0) | ((u32)bfr(ah1) << 16);
    *(float2*)&cs[(size_t)b * Hm + c0] = make_float2(ac0, ac1);
}

// ---------------------------------------------------------------------------
// k_gates_mfma: gates[2048][2048] = Xb(2048x832) @ Wg^T(2048x832), bf16 MFMA.
// ---------------------------------------------------------------------------
__global__ __launch_bounds__(256) void k_gates_mfma(
        const u16* __restrict__ Xb, const u16* __restrict__ Wg,
        float* __restrict__ gates) {
    __shared__ u16 Asl[64 * 32];
    __shared__ u16 Bsl[128 * 32];
    const int m0 = blockIdx.x * 64, n0 = blockIdx.y * 128;
    const int tid = threadIdx.x, lane = tid & 63, wid = tid >> 6;
    const int wr = wid >> 1, wc = wid & 1;
    const int l15 = lane & 15, l4 = lane >> 4;
    const int srow = (wid << 4) + (lane >> 2);
    const int gchunkA = (lane & 3) ^ ((srow >> 1) & 3);
    f32x4 acc[2][4];
    #pragma unroll
    for (int i = 0; i < 2; ++i)
        #pragma unroll
        for (int j = 0; j < 4; ++j) acc[i][j] = (f32x4){0.f, 0.f, 0.f, 0.f};

    for (int k0 = 0; k0 < KWp; k0 += 32) {
        __syncthreads();
        gload16(Xb + (size_t)(m0 + srow) * KWp + k0 + gchunkA * 8, &Asl[wid * 512]);
        #pragma unroll
        for (int j = 0; j < 2; ++j) {
            int brow = (wid << 5) + (j << 4) + (lane >> 2);
            int gchunkB = (lane & 3) ^ ((brow >> 1) & 3);
            gload16(Wg + (size_t)(n0 + brow) * KWp + k0 + gchunkB * 8,
                    &Bsl[wid * 1024 + j * 512]);
        }
        __syncthreads();
        short8 af[2], bf[4];
        #pragma unroll
        for (int mf = 0; mf < 2; ++mf) {
            int r = wr * 32 + mf * 16 + l15;
            af[mf] = *(const short8*)&Asl[r * 32 + (l4 ^ ((r >> 1) & 3)) * 8];
        }
        #pragma unroll
        for (int nf = 0; nf < 4; ++nf) {
            int r = wc * 64 + nf * 16 + l15;
            bf[nf] = *(const short8*)&Bsl[r * 32 + (l4 ^ ((r >> 1) & 3)) * 8];
        }
        #pragma unroll
        for (int mf = 0; mf < 2; ++mf)
            #pragma unroll
            for (int nf = 0; nf < 4; ++nf)
                acc[mf][nf] = __builtin_amdgcn_mfma_f32_16x16x32_bf16(
                                  af[mf], bf[nf], acc[mf][nf], 0, 0, 0);
    }
    #pragma unroll
    for (int mf = 0; mf < 2; ++mf)
        #pragma unroll
        for (int nf = 0; nf < 4; ++nf)
            #pragma unroll
            for (int reg = 0; reg < 4; ++reg) {
                int b = m0 + wr * 32 + mf * 16 + l4 * 4 + reg;
                int n = n0 + wc * 64 + nf * 16 + l15;
                gates[(size_t)b * 2048 + n] = acc[mf][nf][reg];
            }
}

// ---------------------------------------------------------------------------
// k_lstm: elementwise LSTM epilogue over [B,H].
// ---------------------------------------------------------------------------
__global__ __launch_bounds__(256) void k_lstm(
        const float* __restrict__ gates, const float* __restrict__ Wb,
        const float* __restrict__ cs, float* __restrict__ out) {
    const int idx = blockIdx.x * 256 + threadIdx.x;
    const int b = idx >> 9, h = idx & 511;
    const float* g = gates + (size_t)b * 2048;
    float f  = sigmoidf_(g[h]        + Wb[h]);
    float o  = sigmoidf_(g[512 + h]  + Wb[512 + h]);
    float ii = sigmoidf_(g[1024 + h] + Wb[1024 + h]);
    float ch = tanhfast( g[1536 + h] + Wb[1536 + h]);
    float c  = f * cs[idx] + ii * ch;
    out[idx] = o * tanhfast(c);
}

extern "C" void kernel_launch(void* const* d_in, const int* in_sizes, int n_in,
                              void* d_out, int out_size, void* d_ws, size_t ws_size,
                              hipStream_t stream) {
    const float* x      = (const float*)d_in[0];
    const float* h_enc  = (const float*)d_in[1];
    const float* phi    = (const float*)d_in[2];
    const float* cell   = (const float*)d_in[3];
    const float* h_summ = (const float*)d_in[4];
    // d_in[5] c_summ: unused by the reference
    const float* W_w    = (const float*)d_in[6];
    const float* W_b    = (const float*)d_in[7];
    const float* v_w    = (const float*)d_in[8];
    // d_in[9] v_b: softmax-invariant, dropped
    const float* lq_w   = (const float*)d_in[10];
    const float* lq_b   = (const float*)d_in[11];
    const float* lk_w   = (const float*)d_in[12];
    const float* lk_b   = (const float*)d_in[13];
    const float* ls_w   = (const float*)d_in[14];
    const float* ls_b   = (const float*)d_in[15];
    float* out = (float*)d_out;

    char* w = (char*)d_ws;
    // phib: 0 .. 104,857,600 (52.4M bf16). gates (16.78 MB) ALIASES phib:
    // phib's last reader (k_attn) finishes before k_gates_mfma writes gates.
    u16*   phib   = (u16*)  (w);
    float* gates  = (float*)(w);
    float* qs     = (float*)(w + 104857600);                // 4.00 MB
    float* scores = (float*)(w + 109051904);                // 0.40 MB (adjacent to qs)
    float* cs     = (float*)(w + 109461504);                // 4.00 MB
    u16*   Aq     = (u16*)  (w + 113655808);                // 4.19 MB
    u16*   Wq     = (u16*)  (w + 117850112);                // 1.05 MB
    u16*   Wg     = (u16*)  (w + 118898688);                // 3.41 MB
    u16*   Xb     = (u16*)  (w + 122306560);                // 3.41 MB
    u16*   lkwb   = (u16*)  (w + 125714432);                // 0.52 MB
    float* qbias  = (float*)(w + 126763008);                // 2 KB (end ~126.8 MB)

    // one memset covers qs (4MB) + adjacent scores (0.4MB)
    hipMemsetAsync(qs, 0, 4194304 + (size_t)Bm * Tm * sizeof(float), stream);
    k_pack<<<dim3(2048, 6), 256, 0, stream>>>(h_enc, h_summ, lq_w, ls_w, W_w, x, lk_w,
                                              lq_b, ls_b, lk_b,
                                              Aq, Wq, Wg, Xb, lkwb, qbias);
    k_pack_phi<<<dim3(2048), 256, 0, stream>>>(phi, phib);
    k_qs_mfma<<<dim3(Bm / 64, Hm / 64, 2), 256, 0, stream>>>(Aq, Wq, qs);
    k_scores_mfma<<<dim3(3200), 256, 0, stream>>>(phib, lkwb, qs, v_w, qbias, scores);
    k_attn<<<dim3(Bm), 256, 0, stream>>>(phib, cell, scores, Xb, cs);
    k_gates_mfma<<<dim3(Bm / 64, 2048 / 128), 256, 0, stream>>>(Xb, Wg, gates);
    k_lstm<<<dim3((Bm * Hm) / 256), 256, 0, stream>>>(gates, W_b, cs, out);
}

// Round 13
// 308.520 us; speedup vs baseline: 1.2154x; 1.0126x over previous
//
#include <hip/hip_runtime.h>
#include <math.h>

#define Bm 2048
#define Hm 512
#define Em 300
#define Tm 50
#define KWm 812   // H + E
#define KWp 832   // padded to multiple of 32

typedef unsigned short u16;
typedef unsigned int u32;
typedef __attribute__((ext_vector_type(8))) short short8;
typedef __attribute__((ext_vector_type(8))) u16 ushort8v;
typedef __attribute__((ext_vector_type(4))) float f32x4;

__device__ __forceinline__ float sigmoidf_(float x) { return 1.f / (1.f + __expf(-x)); }
// fast tanh: exact at saturation, ~6 VALU ops
__device__ __forceinline__ float tanhfast(float x) { return 1.f - 2.f / (__expf(2.f * x) + 1.f); }

// fp32 -> bf16 bits, round-to-nearest-even
__device__ __forceinline__ u16 bfr(float x) {
    union { float f; u32 u; } c; c.f = x;
    u32 u = c.u;
    u += 0x7FFFu + ((u >> 16) & 1u);
    return (u16)(u >> 16);
}
__device__ __forceinline__ ushort8v cvt8(const float* __restrict__ p) {
    f32x4 v0 = *(const f32x4*)p;
    f32x4 v1 = *(const f32x4*)(p + 4);
    ushort8v r;
    r[0] = bfr(v0[0]); r[1] = bfr(v0[1]); r[2] = bfr(v0[2]); r[3] = bfr(v0[3]);
    r[4] = bfr(v1[0]); r[5] = bfr(v1[1]); r[6] = bfr(v1[2]); r[7] = bfr(v1[3]);
    return r;
}

// async global(bf16,16B) -> LDS, linear dest (wave-uniform base + lane*16)
__device__ __forceinline__ void gload16(const u16* g, u16* l) {
    __builtin_amdgcn_global_load_lds((const __attribute__((address_space(1))) void*)g,
                                     (__attribute__((address_space(3))) void*)l, 16, 0, 0);
}

// ---------------------------------------------------------------------------
// k_prep: ALL prep work in ONE launch so the BW-bound phi conversion overlaps
// the latency-bound qs GEMM and the small packs (same-stream kernels would
// serialize: was pack 15 + pack_phi 50 + qs 18 = 83us of wall time).
// grid (2048, 4):
//  y=0: Wg[2048][832] = bf16(W_w) zero-padded
//  y=1: Xb cols 512.. = bf16(x); r<512: lkwb = bf16(lk_w); r==0: qbias
//  y=2: phib = bf16(phi), grid-stride (the 315MB BW job)
//  y=3 (x<512): qs GEMM tile. z-half trick: idx&1 selects (henc@lq^T) or
//      (hsum@ls^T) -- each half is a SINGLE source matrix (no concat), so
//      qs needs no packed operands: stage fp32->cvt8->swizzled LDS in-loop
//      (R2-validated pattern; VALU cost hides under y=2's BW stalls).
//      atomicAdd into zeroed qs.
// ---------------------------------------------------------------------------
__global__ __launch_bounds__(256) void k_prep(
        const float* __restrict__ henc, const float* __restrict__ hsum,
        const float* __restrict__ lq, const float* __restrict__ ls,
        const float* __restrict__ Ww, const float* __restrict__ x,
        const float* __restrict__ lkw,
        const float* __restrict__ lqb, const float* __restrict__ lsb,
        const float* __restrict__ lkb, const float* __restrict__ phi,
        u16* __restrict__ Wg, u16* __restrict__ Xb, u16* __restrict__ lkwb,
        float* __restrict__ qbias, u16* __restrict__ phib,
        float* __restrict__ qs) {
    const int job = blockIdx.y;
    const int r = blockIdx.x;
    const int tid = threadIdx.x;
    if (job == 0) {
        for (int c = tid; c < KWp; c += 256)
            Wg[(size_t)r * KWp + c] = (c < KWm) ? bfr(Ww[(size_t)r * KWm + c]) : (u16)0;
    } else if (job == 1) {
        for (int c = 512 + tid; c < KWp; c += 256)
            Xb[(size_t)r * KWp + c] = (c < KWm) ? bfr(x[(size_t)r * Em + (c - 512)]) : (u16)0;
        if (r < 512)
            for (int c = tid; c < 512; c += 256)
                lkwb[(size_t)r * 512 + c] = bfr(lkw[(size_t)r * 512 + c]);
        if (r == 0)
            for (int c = tid; c < 512; c += 256)
                qbias[c] = lqb[c] + lsb[c] + lkb[c];
    } else if (job == 2) {
        const size_t nvec = (size_t)Tm * Bm * 512 / 8;
        for (size_t i = (size_t)r * 256 + tid; i < nvec; i += (size_t)2048 * 256)
            *(ushort8v*)&phib[i * 8] = cvt8(phi + i * 8);
    } else {
        if (r >= 512) return;
        __shared__ u16 Asl[64 * 32];
        __shared__ u16 Bsl[64 * 32];
        const int z = r & 1;
        const int n0 = ((r >> 1) & 7) * 64;
        const int m0 = (r >> 4) * 64;
        const float* A = z ? hsum : henc;
        const float* W = z ? ls : lq;
        const int lane = tid & 63, wid = tid >> 6;
        const int wr = wid >> 1, wc = wid & 1;
        const int l15 = lane & 15, l4 = lane >> 4;
        const int srow = tid >> 2;             // 0..63
        const int gch  = tid & 3;              // 8-col group
        const int sslot = gch ^ ((srow >> 1) & 3);
        f32x4 acc[2][2];
        #pragma unroll
        for (int i = 0; i < 2; ++i)
            #pragma unroll
            for (int j = 0; j < 2; ++j) acc[i][j] = (f32x4){0.f, 0.f, 0.f, 0.f};
        for (int k0 = 0; k0 < 512; k0 += 32) {
            __syncthreads();
            *(ushort8v*)&Asl[srow * 32 + sslot * 8] =
                cvt8(A + (size_t)(m0 + srow) * 512 + k0 + gch * 8);
            *(ushort8v*)&Bsl[srow * 32 + sslot * 8] =
                cvt8(W + (size_t)(n0 + srow) * 512 + k0 + gch * 8);
            __syncthreads();
            short8 af[2], bf[2];
            #pragma unroll
            for (int mf = 0; mf < 2; ++mf) {
                int rr = wr * 32 + mf * 16 + l15;
                af[mf] = *(const short8*)&Asl[rr * 32 + (l4 ^ ((rr >> 1) & 3)) * 8];
            }
            #pragma unroll
            for (int nf = 0; nf < 2; ++nf) {
                int rr = wc * 32 + nf * 16 + l15;
                bf[nf] = *(const short8*)&Bsl[rr * 32 + (l4 ^ ((rr >> 1) & 3)) * 8];
            }
            #pragma unroll
            for (int mf = 0; mf < 2; ++mf)
                #pragma unroll
                for (int nf = 0; nf < 2; ++nf)
                    acc[mf][nf] = __builtin_amdgcn_mfma_f32_16x16x32_bf16(
                                      af[mf], bf[nf], acc[mf][nf], 0, 0, 0);
        }
        #pragma unroll
        for (int mf = 0; mf < 2; ++mf)
            #pragma unroll
            for (int nf = 0; nf < 2; ++nf)
                #pragma unroll
                for (int reg = 0; reg < 4; ++reg) {
                    int b = m0 + wr * 32 + mf * 16 + l4 * 4 + reg;
                    int h = n0 + wc * 32 + nf * 16 + l15;
                    atomicAdd(&qs[(size_t)b * Hm + h], acc[mf][nf][reg]);
                }
    }
}

// ---------------------------------------------------------------------------
// k_scores_mfma (dominant) — R7 structure, best measured (~160us):
// BK=64 -> 8 K-iters, single-buffered 32KB LDS, drain __syncthreads,
// 8-chunk XOR swizzle (both-sides involution), XCD-bijective block swizzle,
// setprio(1) around MFMA. Fused fast-tanh/v_w/row-sum epilogue (+qbias),
// atomicAdd into scores.
// ---------------------------------------------------------------------------
__global__ __launch_bounds__(256) void k_scores_mfma(
        const u16* __restrict__ phib, const u16* __restrict__ lkwb,
        const float* __restrict__ qs2, const float* __restrict__ vw,
        const float* __restrict__ qbias, float* __restrict__ scores) {
    __shared__ u16 Asl[128 * 64];
    __shared__ u16 Bsl[128 * 64];
    const int d  = blockIdx.x;
    const int wg = (d & 7) * 400 + (d >> 3);
    const int n0 = (wg & 3) << 7;
    const int m0 = (wg >> 2) << 7;
    const int t  = m0 >> 11;
    const int b0 = m0 & (Bm - 1);
    const int tid = threadIdx.x, lane = tid & 63, wid = tid >> 6;
    const int wr = wid >> 1, wc = wid & 1;
    const int l15 = lane & 15, l4 = lane >> 4;
    const int srow_in = lane >> 3;
    const int schunk  = (lane & 7) ^ srow_in;

    f32x4 acc[4][4];
    #pragma unroll
    for (int i = 0; i < 4; ++i)
        #pragma unroll
        for (int j = 0; j < 4; ++j) acc[i][j] = (f32x4){0.f, 0.f, 0.f, 0.f};

    for (int kt = 0; kt < 8; ++kt) {
        const int k0 = kt << 6;
        __syncthreads();
        #pragma unroll
        for (int j = 0; j < 4; ++j) {
            int r = (wid << 5) + (j << 3) + srow_in;
            gload16(phib + (size_t)(m0 + r) * 512 + k0 + schunk * 8,
                    &Asl[((wid << 5) + (j << 3)) * 64]);
            gload16(lkwb + (size_t)(n0 + r) * 512 + k0 + schunk * 8,
                    &Bsl[((wid << 5) + (j << 3)) * 64]);
        }
        __syncthreads();
        short8 af[4][2], bf[4][2];
        #pragma unroll
        for (int mf = 0; mf < 4; ++mf) {
            int r = wr * 64 + mf * 16 + l15;
            #pragma unroll
            for (int ks = 0; ks < 2; ++ks) {
                int c = ks * 4 + l4;
                af[mf][ks] = *(const short8*)&Asl[r * 64 + (c ^ (r & 7)) * 8];
            }
        }
        #pragma unroll
        for (int nf = 0; nf < 4; ++nf) {
            int r = wc * 64 + nf * 16 + l15;
            #pragma unroll
            for (int ks = 0; ks < 2; ++ks) {
                int c = ks * 4 + l4;
                bf[nf][ks] = *(const short8*)&Bsl[r * 64 + (c ^ (r & 7)) * 8];
            }
        }
        __builtin_amdgcn_s_setprio(1);
        #pragma unroll
        for (int ks = 0; ks < 2; ++ks)
            #pragma unroll
            for (int mf = 0; mf < 4; ++mf)
                #pragma unroll
                for (int nf = 0; nf < 4; ++nf)
                    acc[mf][nf] = __builtin_amdgcn_mfma_f32_16x16x32_bf16(
                                      af[mf][ks], bf[nf][ks], acc[mf][nf], 0, 0, 0);
        __builtin_amdgcn_s_setprio(0);
    }

    float vws[4], qb[4];
    int av[4];
    #pragma unroll
    for (int nf = 0; nf < 4; ++nf) {
        av[nf] = n0 + wc * 64 + nf * 16 + l15;
        vws[nf] = vw[av[nf]];
        qb[nf]  = qbias[av[nf]];
    }
    #pragma unroll
    for (int mf = 0; mf < 4; ++mf) {
        #pragma unroll
        for (int reg = 0; reg < 4; ++reg) {
            int b = b0 + wr * 64 + mf * 16 + l4 * 4 + reg;
            const float* q = qs2 + (size_t)b * Hm;
            float s = 0.f;
            #pragma unroll
            for (int nf = 0; nf < 4; ++nf)
                s = fmaf(tanhfast(acc[mf][nf][reg] + q[av[nf]] + qb[nf]), vws[nf], s);
            #pragma unroll
            for (int o = 1; o < 16; o <<= 1) s += __shfl_xor(s, o);
            if (l15 == 0) atomicAdd(&scores[(size_t)b * Tm + t], s);
        }
    }
}

// ---------------------------------------------------------------------------
// k_attn: softmax over T, weighted sums over bf16 phi + fp32 cell.
// ---------------------------------------------------------------------------
__global__ __launch_bounds__(256) void k_attn(
        const u16* __restrict__ phib, const float* __restrict__ cell,
        const float* __restrict__ scores,
        u16* __restrict__ Xb, float* __restrict__ cs) {
    __shared__ float p[Tm];
    const int b = blockIdx.x;
    const int tid = threadIdx.x;
    if (tid < 64) {
        float s = (tid < Tm) ? scores[(size_t)b * Tm + tid] : -INFINITY;
        float m = s;
        #pragma unroll
        for (int o = 32; o; o >>= 1) m = fmaxf(m, __shfl_xor(m, o));
        float ex = (tid < Tm) ? __expf(s - m) : 0.f;
        float sum = ex;
        #pragma unroll
        for (int o = 32; o; o >>= 1) sum += __shfl_xor(sum, o);
        if (tid < Tm) p[tid] = ex / sum;
    }
    __syncthreads();
    const int c0 = tid * 2;
    float ah0 = 0.f, ah1 = 0.f, ac0 = 0.f, ac1 = 0.f;
    for (int t = 0; t < Tm; ++t) {
        float w = p[t];
        const size_t rb = ((size_t)t * Bm + b) * 512 + c0;
        u32 ph2 = *(const u32*)&phib[rb];
        float2 ce2 = *(const float2*)&cell[rb];
        float p0 = __uint_as_float(ph2 << 16);
        float p1 = __uint_as_float(ph2 & 0xFFFF0000u);
        ah0 = fmaf(w, p0, ah0);
        ah1 = fmaf(w, p1, ah1);
        ac0 = fmaf(w, ce2.x, ac0);
        ac1 = fmaf(w, ce2.y, ac1);
    }
    *(u32*)&Xb[(size_t)b * KWp + c0] = (u32)bfr(ah0) | ((u32)bfr(ah1) << 16);
    *(float2*)&cs[(size_t)b * Hm + c0] = make_float2(ac0, ac1);
}

// ---------------------------------------------------------------------------
// k_gates_mfma R13: gates = Xb(2048x832) @ Wg^T(2048x832), bf16 MFMA.
// BK=64 -> 13 K-iters (was 26 serialized intervals), scores-R7 stage/read
// swizzle scheme, XCD-bijective block swizzle (512 = 8 XCD x 64; same-n
// blocks cluster per XCD -> Wg panel L2-resident, reused 32x).
// ---------------------------------------------------------------------------
__global__ __launch_bounds__(256) void k_gates_mfma(
        const u16* __restrict__ Xb, const u16* __restrict__ Wg,
        float* __restrict__ gates) {
    __shared__ u16 Asl[64 * 64];
    __shared__ u16 Bsl[128 * 64];
    const int d  = blockIdx.x;
    const int wg = (d & 7) * 64 + (d >> 3);
    const int m0 = (wg & 31) << 6;     // 32 m-tiles of 64
    const int n0 = (wg >> 5) << 7;     // 16 n-tiles of 128
    const int tid = threadIdx.x, lane = tid & 63, wid = tid >> 6;
    const int wr = wid >> 1, wc = wid & 1;
    const int l15 = lane & 15, l4 = lane >> 4;
    const int rin = lane >> 3;
    const int schunk = (lane & 7) ^ rin;
    f32x4 acc[2][4];
    #pragma unroll
    for (int i = 0; i < 2; ++i)
        #pragma unroll
        for (int j = 0; j < 4; ++j) acc[i][j] = (f32x4){0.f, 0.f, 0.f, 0.f};

    for (int kt = 0; kt < 13; ++kt) {
        const int k0 = kt << 6;
        __syncthreads();
        #pragma unroll
        for (int j = 0; j < 2; ++j) {
            int r = (wid << 4) + (j << 3) + rin;            // A rows 0..63
            gload16(Xb + (size_t)(m0 + r) * KWp + k0 + schunk * 8,
                    &Asl[((wid << 4) + (j << 3)) * 64]);
        }
        #pragma unroll
        for (int j = 0; j < 4; ++j) {
            int r = (wid << 5) + (j << 3) + rin;            // B rows 0..127
            gload16(Wg + (size_t)(n0 + r) * KWp + k0 + schunk * 8,
                    &Bsl[((wid << 5) + (j << 3)) * 64]);
        }
        __syncthreads();
        short8 af[2][2], bf[4][2];
        #pragma unroll
        for (int mf = 0; mf < 2; ++mf) {
            int r = wr * 32 + mf * 16 + l15;
            #pragma unroll
            for (int ks = 0; ks < 2; ++ks) {
                int c = ks * 4 + l4;
                af[mf][ks] = *(const short8*)&Asl[r * 64 + (c ^ (r & 7)) * 8];
            }
        }
        #pragma unroll
        for (int nf = 0; nf < 4; ++nf) {
            int r = wc * 64 + nf * 16 + l15;
            #pragma unroll
            for (int ks = 0; ks < 2; ++ks) {
                int c = ks * 4 + l4;
                bf[nf][ks] = *(const short8*)&Bsl[r * 64 + (c ^ (r & 7)) * 8];
            }
        }
        __builtin_amdgcn_s_setprio(1);
        #pragma unroll
        for (int ks = 0; ks < 2; ++ks)
            #pragma unroll
            for (int mf = 0; mf < 2; ++mf)
                #pragma unroll
                for (int nf = 0; nf < 4; ++nf)
                    acc[mf][nf] = __builtin_amdgcn_mfma_f32_16x16x32_bf16(
                                      af[mf][ks], bf[nf][ks], acc[mf][nf], 0, 0, 0);
        __builtin_amdgcn_s_setprio(0);
    }
    #pragma unroll
    for (int mf = 0; mf < 2; ++mf)
        #pragma unroll
        for (int nf = 0; nf < 4; ++nf)
            #pragma unroll
            for (int reg = 0; reg < 4; ++reg) {
                int b = m0 + wr * 32 + mf * 16 + l4 * 4 + reg;
                int n = n0 + wc * 64 + nf * 16 + l15;
                gates[(size_t)b * 2048 + n] = acc[mf][nf][reg];
            }
}

// ---------------------------------------------------------------------------
// k_lstm: elementwise LSTM epilogue over [B,H].
// ---------------------------------------------------------------------------
__global__ __launch_bounds__(256) void k_lstm(
        const float* __restrict__ gates, const float* __restrict__ Wb,
        const float* __restrict__ cs, float* __restrict__ out) {
    const int idx = blockIdx.x * 256 + threadIdx.x;
    const int b = idx >> 9, h = idx & 511;
    const float* g = gates + (size_t)b * 2048;
    float f  = sigmoidf_(g[h]        + Wb[h]);
    float o  = sigmoidf_(g[512 + h]  + Wb[512 + h]);
    float ii = sigmoidf_(g[1024 + h] + Wb[1024 + h]);
    float ch = tanhfast( g[1536 + h] + Wb[1536 + h]);
    float c  = f * cs[idx] + ii * ch;
    out[idx] = o * tanhfast(c);
}

extern "C" void kernel_launch(void* const* d_in, const int* in_sizes, int n_in,
                              void* d_out, int out_size, void* d_ws, size_t ws_size,
                              hipStream_t stream) {
    const float* x      = (const float*)d_in[0];
    const float* h_enc  = (const float*)d_in[1];
    const float* phi    = (const float*)d_in[2];
    const float* cell   = (const float*)d_in[3];
    const float* h_summ = (const float*)d_in[4];
    // d_in[5] c_summ: unused by the reference
    const float* W_w    = (const float*)d_in[6];
    const float* W_b    = (const float*)d_in[7];
    const float* v_w    = (const float*)d_in[8];
    // d_in[9] v_b: softmax-invariant, dropped
    const float* lq_w   = (const float*)d_in[10];
    const float* lq_b   = (const float*)d_in[11];
    const float* lk_w   = (const float*)d_in[12];
    const float* lk_b   = (const float*)d_in[13];
    const float* ls_w   = (const float*)d_in[14];
    const float* ls_b   = (const float*)d_in[15];
    float* out = (float*)d_out;

    char* w = (char*)d_ws;
    // phib: 0 .. 104,857,600 (52.4M bf16). gates (16.78 MB) ALIASES phib:
    // phib's last reader (k_attn) finishes before k_gates_mfma writes gates.
    u16*   phib   = (u16*)  (w);
    float* gates  = (float*)(w);
    float* qs     = (float*)(w + 104857600);                // 4.00 MB
    float* scores = (float*)(w + 109051904);                // 0.40 MB (adjacent to qs)
    float* cs     = (float*)(w + 109461504);                // 4.00 MB
    u16*   Wg     = (u16*)  (w + 113655808);                // 3.41 MB
    u16*   Xb     = (u16*)  (w + 117063680);                // 3.41 MB
    u16*   lkwb   = (u16*)  (w + 120471552);                // 0.52 MB
    float* qbias  = (float*)(w + 121520128);                // 2 KB (end ~121.6 MB)

    // one memset covers qs (4MB) + adjacent scores (0.4MB)
    hipMemsetAsync(qs, 0, 4194304 + (size_t)Bm * Tm * sizeof(float), stream);
    k_prep<<<dim3(2048, 4), 256, 0, stream>>>(h_enc, h_summ, lq_w, ls_w, W_w, x, lk_w,
                                              lq_b, ls_b, lk_b, phi,
                                              Wg, Xb, lkwb, qbias, phib, qs);
    k_scores_mfma<<<dim3(3200), 256, 0, stream>>>(phib, lkwb, qs, v_w, qbias, scores);
    k_attn<<<dim3(Bm), 256, 0, stream>>>(phib, cell, scores, Xb, cs);
    k_gates_mfma<<<dim3(512), 256, 0, stream>>>(Xb, Wg, gates);
    k_lstm<<<dim3((Bm * Hm) / 256), 256, 0, stream>>>(gates, W_b, cs, out);
}